// Round 3
// baseline (80.718 us; speedup 1.0000x reference)
//
#include <hip/hip_runtime.h>

typedef __attribute__((ext_vector_type(8))) short short8;
typedef __attribute__((ext_vector_type(4))) float f32x4;

__global__ __launch_bounds__(512) void crf_fused_kernel(
    const float* __restrict__ H, const float* __restrict__ W,
    const float* __restrict__ bias,
    const float* __restrict__ startT, const float* __restrict__ endT,
    const float* __restrict__ trans,
    const int* __restrict__ y, const int* __restrict__ y_len,
    float* __restrict__ out)
{
  // staging: aTh 16K | aTl 16K | bTh 24K | bTl 24K = 80K, union'd with P[128][196]
  __shared__ __align__(16) float smem[25088];     // 100352 B
  __shared__ __align__(16) float sc[128][64];     // 32768 B
  __shared__ float scm[128];
  __shared__ __align__(16) float ubuf[64];
  unsigned char* aTh = (unsigned char*)smem;
  unsigned char* aTl = aTh + 16384;
  unsigned char* bTh = aTh + 32768;
  unsigned char* bTl = aTh + 57344;
  float* P = smem;  // [128][196]

  const int b    = blockIdx.x;
  const int tid  = threadIdx.x;
  const int lane = tid & 63;
  const int wid  = tid >> 6;
  const int wm   = wid >> 2;
  const int wn   = wid & 3;

  f32x4 acc[4][3] = {};
  const float* Hb = H + (size_t)b * (128 * 512);

  float4 areg[4], breg[6];
  int aRow[4], aK4[4], bN[6], bK4[6];
  #pragma unroll
  for (int it = 0; it < 4; ++it) { int i = it * 512 + tid; aRow[it] = i >> 4; aK4[it] = i & 15; }
  #pragma unroll
  for (int it = 0; it < 6; ++it) { int i = it * 512 + tid; bN[it] = i >> 4; bK4[it] = i & 15; }

  #pragma unroll
  for (int it = 0; it < 4; ++it)
    areg[it] = ((const float4*)(Hb + aRow[it] * 512))[aK4[it]];
  #pragma unroll
  for (int it = 0; it < 6; ++it)
    breg[it] = ((const float4*)(W + (bN[it] & 63) * 1536 + (bN[it] >> 6) * 512))[bK4[it]];

  for (int kk = 0; kk < 512; kk += 64) {
    if (kk) __syncthreads();
    // ---- stage hi/lo (truncation split: hi=trunc16(v), lo=trunc16(v-hi)) ----
    #pragma unroll
    for (int it = 0; it < 4; ++it) {
      float4 v = areg[it];
      unsigned ux = __float_as_uint(v.x), uy = __float_as_uint(v.y);
      unsigned uz = __float_as_uint(v.z), uw = __float_as_uint(v.w);
      uint2 hi; hi.x = (ux >> 16) | (uy & 0xFFFF0000u); hi.y = (uz >> 16) | (uw & 0xFFFF0000u);
      float rx = v.x - __uint_as_float(ux & 0xFFFF0000u);
      float ry = v.y - __uint_as_float(uy & 0xFFFF0000u);
      float rz = v.z - __uint_as_float(uz & 0xFFFF0000u);
      float rw = v.w - __uint_as_float(uw & 0xFFFF0000u);
      uint2 lo; lo.x = (__float_as_uint(rx) >> 16) | (__float_as_uint(ry) & 0xFFFF0000u);
      lo.y = (__float_as_uint(rz) >> 16) | (__float_as_uint(rw) & 0xFFFF0000u);
      int off = aRow[it] * 128 + ((aK4[it] * 8) ^ ((aRow[it] & 7) << 4));
      *(uint2*)(aTh + off) = hi; *(uint2*)(aTl + off) = lo;
    }
    #pragma unroll
    for (int it = 0; it < 6; ++it) {
      float4 v = breg[it];
      unsigned ux = __float_as_uint(v.x), uy = __float_as_uint(v.y);
      unsigned uz = __float_as_uint(v.z), uw = __float_as_uint(v.w);
      uint2 hi; hi.x = (ux >> 16) | (uy & 0xFFFF0000u); hi.y = (uz >> 16) | (uw & 0xFFFF0000u);
      float rx = v.x - __uint_as_float(ux & 0xFFFF0000u);
      float ry = v.y - __uint_as_float(uy & 0xFFFF0000u);
      float rz = v.z - __uint_as_float(uz & 0xFFFF0000u);
      float rw = v.w - __uint_as_float(uw & 0xFFFF0000u);
      uint2 lo; lo.x = (__float_as_uint(rx) >> 16) | (__float_as_uint(ry) & 0xFFFF0000u);
      lo.y = (__float_as_uint(rz) >> 16) | (__float_as_uint(rw) & 0xFFFF0000u);
      int off = bN[it] * 128 + ((bK4[it] * 8) ^ ((bN[it] & 7) << 4));
      *(uint2*)(bTh + off) = hi; *(uint2*)(bTl + off) = lo;
    }
    __syncthreads();
    if (kk < 448) {
      #pragma unroll
      for (int it = 0; it < 4; ++it)
        areg[it] = ((const float4*)(Hb + aRow[it] * 512 + kk + 64))[aK4[it]];
      #pragma unroll
      for (int it = 0; it < 6; ++it)
        breg[it] = ((const float4*)(W + (bN[it] & 63) * 1536 + (bN[it] >> 6) * 512 + kk + 64))[bK4[it]];
    }
    #pragma unroll
    for (int ks = 0; ks < 2; ++ks) {
      const int kbyte = ks * 64 + ((lane >> 4) << 4);
      short8 ah[4], al[4], bh[3], bl[3];
      #pragma unroll
      for (int m = 0; m < 4; ++m) {
        int row = wm * 64 + m * 16 + (lane & 15);
        int off = row * 128 + (kbyte ^ ((row & 7) << 4));
        ah[m] = *(const short8*)(aTh + off);
        al[m] = *(const short8*)(aTl + off);
      }
      #pragma unroll
      for (int n = 0; n < 3; ++n) {
        int col = wn * 48 + n * 16 + (lane & 15);
        int off = col * 128 + (kbyte ^ ((col & 7) << 4));
        bh[n] = *(const short8*)(bTh + off);
        bl[n] = *(const short8*)(bTl + off);
      }
      #pragma unroll
      for (int m = 0; m < 4; ++m)
        #pragma unroll
        for (int n = 0; n < 3; ++n) {
          asm("v_mfma_f32_16x16x32_bf16 %0, %1, %2, %0"
              : "+v"(acc[m][n]) : "v"(ah[m]), "v"(bh[n]));
          asm("v_mfma_f32_16x16x32_bf16 %0, %1, %2, %0"
              : "+v"(acc[m][n]) : "v"(al[m]), "v"(bh[n]));
          asm("v_mfma_f32_16x16x32_bf16 %0, %1, %2, %0"
              : "+v"(acc[m][n]) : "v"(ah[m]), "v"(bl[n]));
        }
    }
  }
  __syncthreads();

  #pragma unroll
  for (int m = 0; m < 4; ++m)
    #pragma unroll
    for (int n = 0; n < 3; ++n) {
      int row0 = wm * 64 + m * 16 + ((lane >> 4) << 2);
      int col  = wn * 48 + n * 16 + (lane & 15);
      #pragma unroll
      for (int j = 0; j < 4; ++j)
        P[(row0 + j) * 196 + col] = acc[m][n][j];
    }
  __syncthreads();

  #pragma unroll
  for (int it = 0; it < 4; ++it) {
    int i4 = it * 512 + tid;
    int t = i4 >> 4, c4 = i4 & 15;
    float4 s = *(const float4*)(P + t * 196 + 64 + c4 * 4);
    float4 bb = ((const float4*)bias)[c4];
    s.x += bb.x; s.y += bb.y; s.z += bb.z; s.w += bb.w;
    if (t > 0) {
      float4 g = *(const float4*)(P + (t - 1) * 196 + c4 * 4);
      s.x += g.x; s.y += g.y; s.z += g.z; s.w += g.w;
    }
    if (t < 127) {
      float4 g = *(const float4*)(P + (t + 1) * 196 + 128 + c4 * 4);
      s.x += g.x; s.y += g.y; s.z += g.z; s.w += g.w;
    }
    *(float4*)(&sc[t][c4 * 4]) = s;
  }
  __syncthreads();

  const int len = y_len[b];
  const int* yb = y + b * 128;

  // ---- numerator (wave 0) concurrent with row-max (all waves) ----
  float num = 0.f;
  if (wid == 0) {
    float p = 0.f;
    #pragma unroll
    for (int rep = 0; rep < 2; ++rep) {
      int t = lane + rep * 64;
      if (t < 127) {
        int yt = yb[t], yt1 = yb[t + 1];
        if (t < len)     p += sc[t][yt];
        if (t + 1 < len) p += trans[yt * 64 + yt1];
      }
    }
    #pragma unroll
    for (int s = 32; s > 0; s >>= 1) p += __shfl_xor(p, s, 64);
    num = p + startT[yb[0]] + endT[yb[len - 1]];
    if (len == 128) num += sc[127][yb[127]];
  }
  #pragma unroll
  for (int r = 0; r < 16; ++r) {
    int row = wid * 16 + r;
    float x = sc[row][lane];
    #pragma unroll
    for (int s = 32; s > 0; s >>= 1) x = fmaxf(x, __shfl_xor(x, s, 64));
    if (lane == 0) scm[row] = x;
  }
  __syncthreads();

  // ---- transform: sc[t][c] <- exp(sc - m_t), parallel ----
  {
    int row = tid >> 2, c0 = (tid & 3) << 4;
    float mt = scm[row];
    float4* p4 = (float4*)&sc[row][c0];
    #pragma unroll
    for (int j = 0; j < 4; ++j) {
      float4 x = p4[j];
      x.x = __expf(x.x - mt); x.y = __expf(x.y - mt);
      x.z = __expf(x.z - mt); x.w = __expf(x.w - mt);
      p4[j] = x;
    }
  }
  __syncthreads();
  if (wid != 0) return;

  // ---- wave-0 exp-space scan: u <- (u . E) * scExp[t], logscale += m_t ----
  float e[64];
  #pragma unroll
  for (int c = 0; c < 64; ++c) e[c] = __expf(trans[c * 64 + lane]);
  float eS = __expf(startT[lane]);
  float eE = __expf(endT[lane]);

  float u = eS * sc[0][lane];
  float logscale = scm[0];

  for (int t = 1; t < len; ++t) {
    float scv = sc[t][lane];   // independent loads, issue early
    float mt  = scm[t];
    ubuf[lane] = u;
    const float4* u4 = (const float4*)ubuf;
    float vv[8] = {0.f, 0.f, 0.f, 0.f, 0.f, 0.f, 0.f, 0.f};
    #pragma unroll
    for (int i = 0; i < 8; ++i) {
      float4 ua = u4[2 * i], ub = u4[2 * i + 1];
      vv[0] = fmaf(ua.x, e[8 * i + 0], vv[0]);
      vv[1] = fmaf(ua.y, e[8 * i + 1], vv[1]);
      vv[2] = fmaf(ua.z, e[8 * i + 2], vv[2]);
      vv[3] = fmaf(ua.w, e[8 * i + 3], vv[3]);
      vv[4] = fmaf(ub.x, e[8 * i + 4], vv[4]);
      vv[5] = fmaf(ub.y, e[8 * i + 5], vv[5]);
      vv[6] = fmaf(ub.z, e[8 * i + 6], vv[6]);
      vv[7] = fmaf(ub.w, e[8 * i + 7], vv[7]);
    }
    float v = ((vv[0] + vv[1]) + (vv[2] + vv[3])) + ((vv[4] + vv[5]) + (vv[6] + vv[7]));
    u = v * scv;
    logscale += mt;
    if ((t & 7) == 0) {  // exact power-of-2 renorm (growth <= 2^60 per 8 steps)
      float r = u;
      #pragma unroll
      for (int s = 32; s > 0; s >>= 1) r = fmaxf(r, __shfl_xor(r, s, 64));
      unsigned br = __float_as_uint(r) & 0x7F800000u;
      float inv = __uint_as_float(0x7F000000u - br);   // 2^(127-e) exact
      u *= inv;
      logscale += (float)((int)(br >> 23) - 127) * 0.69314718055994531f;
    }
  }

  float x = u * eE;
  #pragma unroll
  for (int s = 32; s > 0; s >>= 1) x += __shfl_xor(x, s, 64);
  if (lane == 0) out[b] = num - (__logf(x) + logscale);
}

extern "C" void kernel_launch(void* const* d_in, const int* in_sizes, int n_in,
                              void* d_out, int out_size, void* d_ws, size_t ws_size,
                              hipStream_t stream) {
  const float* H      = (const float*)d_in[0];
  const float* W      = (const float*)d_in[1];
  const float* bias   = (const float*)d_in[2];
  const float* startT = (const float*)d_in[3];
  const float* endT   = (const float*)d_in[4];
  const float* trans  = (const float*)d_in[5];
  const int*   y      = (const int*)d_in[6];
  const int*   y_len  = (const int*)d_in[8];
  float* out = (float*)d_out;

  crf_fused_kernel<<<dim3(256), dim3(512), 0, stream>>>(
      H, W, bias, startT, endT, trans, y, y_len, out);
}

// Round 4
// 55.740 us; speedup vs baseline: 1.4481x; 1.4481x over previous
//
#include <hip/hip_runtime.h>

typedef __attribute__((ext_vector_type(8))) short short8;
typedef __attribute__((ext_vector_type(4))) float f32x4;

__device__ __forceinline__ unsigned short f2bf(float x) {
  unsigned int u = __float_as_uint(x);
  u += 0x7FFFu + ((u >> 16) & 1u);
  return (unsigned short)(u >> 16);
}
__device__ __forceinline__ float bf2f(unsigned short h) {
  return __uint_as_float(((unsigned)h) << 16);
}

__global__ __launch_bounds__(512) void crf_fused_kernel(
    const float* __restrict__ H, const float* __restrict__ W,
    const float* __restrict__ bias,
    const float* __restrict__ startT, const float* __restrict__ endT,
    const float* __restrict__ trans,
    const int* __restrict__ y, const int* __restrict__ y_len,
    float* __restrict__ out)
{
  // region0 union: GEMM staging (80K) / P[128][196] f32 (100,352B) /
  //                scan: EA bf16[64][128B] (8K) + Mbuf[8] bf16[64][128B] (64K)
  __shared__ __align__(16) float smem[25088];
  __shared__ __align__(16) float sc[128][64];     // scores then sexp
  __shared__ float scm[128];
  __shared__ __align__(16) float ubuf[64];
  unsigned char* aTh = (unsigned char*)smem;
  unsigned char* aTl = aTh + 16384;
  unsigned char* bTh = aTh + 32768;
  unsigned char* bTl = aTh + 57344;
  float* P = smem;  // [128][196]
  unsigned char* EA    = (unsigned char*)smem;          // scan phase
  unsigned char* Mbase = ((unsigned char*)smem) + 8192; // 8 x 8KB

  const int b    = blockIdx.x;
  const int tid  = threadIdx.x;
  const int lane = tid & 63;
  const int wid  = tid >> 6;
  const int wm   = wid >> 2;
  const int wn   = wid & 3;

  f32x4 acc[4][3] = {};
  const float* Hb = H + (size_t)b * (128 * 512);

  // ================= GEMM (hi/lo split bf16 MFMA) =================
  float4 areg[4], breg[6];
  int aRow[4], aK4[4], bN[6], bK4[6];
  #pragma unroll
  for (int it = 0; it < 4; ++it) { int i = it * 512 + tid; aRow[it] = i >> 4; aK4[it] = i & 15; }
  #pragma unroll
  for (int it = 0; it < 6; ++it) { int i = it * 512 + tid; bN[it] = i >> 4; bK4[it] = i & 15; }

  #pragma unroll
  for (int it = 0; it < 4; ++it)
    areg[it] = ((const float4*)(Hb + aRow[it] * 512))[aK4[it]];
  #pragma unroll
  for (int it = 0; it < 6; ++it)
    breg[it] = ((const float4*)(W + (bN[it] & 63) * 1536 + (bN[it] >> 6) * 512))[bK4[it]];

  for (int kk = 0; kk < 512; kk += 64) {
    if (kk) __syncthreads();
    #pragma unroll
    for (int it = 0; it < 4; ++it) {
      float4 v = areg[it];
      unsigned ux = __float_as_uint(v.x), uy = __float_as_uint(v.y);
      unsigned uz = __float_as_uint(v.z), uw = __float_as_uint(v.w);
      uint2 hi; hi.x = (ux >> 16) | (uy & 0xFFFF0000u); hi.y = (uz >> 16) | (uw & 0xFFFF0000u);
      float rx = v.x - __uint_as_float(ux & 0xFFFF0000u);
      float ry = v.y - __uint_as_float(uy & 0xFFFF0000u);
      float rz = v.z - __uint_as_float(uz & 0xFFFF0000u);
      float rw = v.w - __uint_as_float(uw & 0xFFFF0000u);
      uint2 lo; lo.x = (__float_as_uint(rx) >> 16) | (__float_as_uint(ry) & 0xFFFF0000u);
      lo.y = (__float_as_uint(rz) >> 16) | (__float_as_uint(rw) & 0xFFFF0000u);
      int off = aRow[it] * 128 + ((aK4[it] * 8) ^ ((aRow[it] & 7) << 4));
      *(uint2*)(aTh + off) = hi; *(uint2*)(aTl + off) = lo;
    }
    #pragma unroll
    for (int it = 0; it < 6; ++it) {
      float4 v = breg[it];
      unsigned ux = __float_as_uint(v.x), uy = __float_as_uint(v.y);
      unsigned uz = __float_as_uint(v.z), uw = __float_as_uint(v.w);
      uint2 hi; hi.x = (ux >> 16) | (uy & 0xFFFF0000u); hi.y = (uz >> 16) | (uw & 0xFFFF0000u);
      float rx = v.x - __uint_as_float(ux & 0xFFFF0000u);
      float ry = v.y - __uint_as_float(uy & 0xFFFF0000u);
      float rz = v.z - __uint_as_float(uz & 0xFFFF0000u);
      float rw = v.w - __uint_as_float(uw & 0xFFFF0000u);
      uint2 lo; lo.x = (__float_as_uint(rx) >> 16) | (__float_as_uint(ry) & 0xFFFF0000u);
      lo.y = (__float_as_uint(rz) >> 16) | (__float_as_uint(rw) & 0xFFFF0000u);
      int off = bN[it] * 128 + ((bK4[it] * 8) ^ ((bN[it] & 7) << 4));
      *(uint2*)(bTh + off) = hi; *(uint2*)(bTl + off) = lo;
    }
    __syncthreads();
    if (kk < 448) {
      #pragma unroll
      for (int it = 0; it < 4; ++it)
        areg[it] = ((const float4*)(Hb + aRow[it] * 512 + kk + 64))[aK4[it]];
      #pragma unroll
      for (int it = 0; it < 6; ++it)
        breg[it] = ((const float4*)(W + (bN[it] & 63) * 1536 + (bN[it] >> 6) * 512 + kk + 64))[bK4[it]];
    }
    #pragma unroll
    for (int ks = 0; ks < 2; ++ks) {
      const int kbyte = ks * 64 + ((lane >> 4) << 4);
      short8 ah[4], al[4], bh[3], bl[3];
      #pragma unroll
      for (int m = 0; m < 4; ++m) {
        int row = wm * 64 + m * 16 + (lane & 15);
        int off = row * 128 + (kbyte ^ ((row & 7) << 4));
        ah[m] = *(const short8*)(aTh + off);
        al[m] = *(const short8*)(aTl + off);
      }
      #pragma unroll
      for (int n = 0; n < 3; ++n) {
        int col = wn * 48 + n * 16 + (lane & 15);
        int off = col * 128 + (kbyte ^ ((col & 7) << 4));
        bh[n] = *(const short8*)(bTh + off);
        bl[n] = *(const short8*)(bTl + off);
      }
      #pragma unroll
      for (int m = 0; m < 4; ++m)
        #pragma unroll
        for (int n = 0; n < 3; ++n) {
          asm("v_mfma_f32_16x16x32_bf16 %0, %1, %2, %0"
              : "+v"(acc[m][n]) : "v"(ah[m]), "v"(bh[n]));
          asm("v_mfma_f32_16x16x32_bf16 %0, %1, %2, %0"
              : "+v"(acc[m][n]) : "v"(al[m]), "v"(bh[n]));
          asm("v_mfma_f32_16x16x32_bf16 %0, %1, %2, %0"
              : "+v"(acc[m][n]) : "v"(ah[m]), "v"(bl[n]));
        }
    }
  }
  __syncthreads();

  // acc -> P
  #pragma unroll
  for (int m = 0; m < 4; ++m)
    #pragma unroll
    for (int n = 0; n < 3; ++n) {
      int row0 = wm * 64 + m * 16 + ((lane >> 4) << 2);
      int col  = wn * 48 + n * 16 + (lane & 15);
      #pragma unroll
      for (int j = 0; j < 4; ++j)
        P[(row0 + j) * 196 + col] = acc[m][n][j];
    }
  __syncthreads();

  // epilogue: P -> sc (raw scores)
  #pragma unroll
  for (int it = 0; it < 4; ++it) {
    int i4 = it * 512 + tid;
    int t = i4 >> 4, c4 = i4 & 15;
    float4 s = *(const float4*)(P + t * 196 + 64 + c4 * 4);
    float4 bb = ((const float4*)bias)[c4];
    s.x += bb.x; s.y += bb.y; s.z += bb.z; s.w += bb.w;
    if (t > 0) {
      float4 g = *(const float4*)(P + (t - 1) * 196 + c4 * 4);
      s.x += g.x; s.y += g.y; s.z += g.z; s.w += g.w;
    }
    if (t < 127) {
      float4 g = *(const float4*)(P + (t + 1) * 196 + 128 + c4 * 4);
      s.x += g.x; s.y += g.y; s.z += g.z; s.w += g.w;
    }
    *(float4*)(&sc[t][c4 * 4]) = s;
  }
  __syncthreads();

  const int len = y_len[b];
  const int* yb = y + b * 128;

  // ---- numerator (wave 0) + row max (all waves), on RAW sc ----
  float num = 0.f;
  if (wid == 0) {
    float p = 0.f;
    #pragma unroll
    for (int rep = 0; rep < 2; ++rep) {
      int t = lane + rep * 64;
      if (t < 127) {
        int yt = yb[t], yt1 = yb[t + 1];
        if (t < len)     p += sc[t][yt];
        if (t + 1 < len) p += trans[yt * 64 + yt1];
      }
    }
    #pragma unroll
    for (int s = 32; s > 0; s >>= 1) p += __shfl_xor(p, s, 64);
    num = p + startT[yb[0]] + endT[yb[len - 1]];
    if (len == 128) num += sc[127][yb[127]];
  }
  #pragma unroll
  for (int r = 0; r < 16; ++r) {
    int row = wid * 16 + r;
    float x = sc[row][lane];
    #pragma unroll
    for (int s = 32; s > 0; s >>= 1) x = fmaxf(x, __shfl_xor(x, s, 64));
    if (lane == 0) scm[row] = x;
  }
  __syncthreads();

  // ---- transform sc -> sexp = exp(sc - m_t); build EA = exp(trans^T - 1) bf16;
  //      init own Mbuf = I (wave-local) ----
  {
    int row = tid >> 2, c0 = (tid & 3) << 4;
    float mt = scm[row];
    float4* p4 = (float4*)&sc[row][c0];
    #pragma unroll
    for (int j = 0; j < 4; ++j) {
      float4 x = p4[j];
      x.x = __expf(x.x - mt); x.y = __expf(x.y - mt);
      x.z = __expf(x.z - mt); x.w = __expf(x.w - mt);
      p4[j] = x;
    }
  }
  {
    int r = tid >> 3, g = tid & 7;   // EA[r][k] = exp(trans[k][r] - 1)
    #pragma unroll
    for (int j = 0; j < 8; j += 2) {
      int k = g * 8 + j;
      float v0 = __expf(trans[k * 64 + r] - 1.0f);
      float v1 = __expf(trans[(k + 1) * 64 + r] - 1.0f);
      unsigned pk = ((unsigned)f2bf(v1) << 16) | (unsigned)f2bf(v0);
      *(unsigned*)(EA + r * 128 + ((2 * k) ^ ((r & 7) << 4))) = pk;
    }
  }
  {
    unsigned char* Mb = Mbase + wid * 8192;
    uint4 z = {0u, 0u, 0u, 0u};
    #pragma unroll
    for (int j = 0; j < 8; ++j)
      *(uint4*)(Mb + lane * 128 + j * 16) = z;
    *(unsigned short*)(Mb + lane * 128 + ((2 * lane) ^ ((lane & 7) << 4))) = 0x3F80;
  }
  __syncthreads();

  // ---- chunk phase: wave w computes B_w = prod A_t over t in [16w,16w+15]&[1,len-1]
  //      maintained row-major in Mbuf; iteration computes B_new^T = D_t E^T B_old^T
  {
    unsigned char* Mb = Mbase + wid * 8192;
    short8 ea[4][2];
    #pragma unroll
    for (int rt = 0; rt < 4; ++rt)
      #pragma unroll
      for (int kh = 0; kh < 2; ++kh) {
        int row = rt * 16 + (lane & 15);
        int kb = kh * 64 + ((lane >> 4) << 4);
        ea[rt][kh] = *(const short8*)(EA + row * 128 + (kb ^ ((row & 7) << 4)));
      }
    f32x4 z4 = {0.f, 0.f, 0.f, 0.f};

    int t0 = (wid == 0) ? 1 : 16 * wid;
    int t1 = 16 * wid + 15; if (t1 > len - 1) t1 = len - 1;
    for (int t = t0; t <= t1; ++t) {
      short8 mf[4][2];
      #pragma unroll
      for (int ct = 0; ct < 4; ++ct)
        #pragma unroll
        for (int kh = 0; kh < 2; ++kh) {
          int row = ct * 16 + (lane & 15);
          int kb = kh * 64 + ((lane >> 4) << 4);
          mf[ct][kh] = *(const short8*)(Mb + row * 128 + (kb ^ ((row & 7) << 4)));
        }
      f32x4 sv[4];
      #pragma unroll
      for (int rt = 0; rt < 4; ++rt)
        sv[rt] = *(const f32x4*)(&sc[t][rt * 16 + ((lane >> 4) << 2)]);

      f32x4 c[4][4];
      #pragma unroll
      for (int rt = 0; rt < 4; ++rt)
        #pragma unroll
        for (int ct = 0; ct < 4; ++ct) {
          asm("v_mfma_f32_16x16x32_bf16 %0, %1, %2, %3"
              : "=&v"(c[rt][ct]) : "v"(ea[rt][0]), "v"(mf[ct][0]), "v"(z4));
          asm("v_mfma_f32_16x16x32_bf16 %0, %1, %2, %0"
              : "+v"(c[rt][ct]) : "v"(ea[rt][1]), "v"(mf[ct][1]));
        }
      #pragma unroll
      for (int rt = 0; rt < 4; ++rt)
        #pragma unroll
        for (int ct = 0; ct < 4; ++ct) {
          f32x4 cc = c[rt][ct] * sv[rt];   // scale rows R by s[R]
          unsigned p0, p1;
          asm("v_cvt_pk_bf16_f32 %0, %1, %2" : "=v"(p0) : "v"(cc[0]), "v"(cc[1]));
          asm("v_cvt_pk_bf16_f32 %0, %1, %2" : "=v"(p1) : "v"(cc[2]), "v"(cc[3]));
          uint2 w2; w2.x = p0; w2.y = p1;
          int row = ct * 16 + (lane & 15);                     // = C
          int byt = 2 * (rt * 16 + ((lane >> 4) << 2));        // = 2R
          *(uint2*)(Mb + row * 128 + (byt ^ ((row & 7) << 4))) = w2;
        }
    }
  }
  __syncthreads();
  if (wid != 0) return;

  // ---- wave 0: combine u^T B_0 ... B_7, then logZ ----
  float eE = __expf(endT[lane]);
  float ls;
  {
    int t1 = 1 + lane, t2 = 65 + lane;
    float a = (t1 <= len - 1) ? (scm[t1] + 1.0f) : 0.f;
    if (t2 <= len - 1) a += scm[t2] + 1.0f;
    #pragma unroll
    for (int s = 32; s > 0; s >>= 1) a += __shfl_xor(a, s, 64);
    ls = a + scm[0];
  }
  float u = __expf(startT[lane]) * sc[0][lane];

  for (int k = 0; k < 8; ++k) {
    if (16 * k >= len) break;
    int lo = (k == 0) ? 1 : 16 * k;
    int hi = 16 * k + 15; if (hi > len - 1) hi = len - 1;
    if (lo > hi) continue;
    // power-of-2 renorm of u
    float r = u;
    #pragma unroll
    for (int s = 32; s > 0; s >>= 1) r = fmaxf(r, __shfl_xor(r, s, 64));
    unsigned br = __float_as_uint(r) & 0x7F800000u;
    u *= __uint_as_float(0x7F000000u - br);
    ls += (float)((int)(br >> 23) - 127) * 0.69314718055994531f;
    // matvec v[c'] = sum_c u[c] * B_k[c][c']
    const unsigned char* Mb = Mbase + k * 8192;
    ubuf[lane] = u;
    float v = 0.f;
    #pragma unroll 4
    for (int c = 0; c < 64; c += 4) {
      float4 uu = *(const float4*)&ubuf[c];
      float m0 = bf2f(*(const unsigned short*)(Mb + (c + 0) * 128 + ((2 * lane) ^ (((c + 0) & 7) << 4))));
      float m1 = bf2f(*(const unsigned short*)(Mb + (c + 1) * 128 + ((2 * lane) ^ (((c + 1) & 7) << 4))));
      float m2 = bf2f(*(const unsigned short*)(Mb + (c + 2) * 128 + ((2 * lane) ^ (((c + 2) & 7) << 4))));
      float m3 = bf2f(*(const unsigned short*)(Mb + (c + 3) * 128 + ((2 * lane) ^ (((c + 3) & 7) << 4))));
      v = fmaf(uu.x, m0, v);
      v = fmaf(uu.y, m1, v);
      v = fmaf(uu.z, m2, v);
      v = fmaf(uu.w, m3, v);
    }
    u = v;
  }

  float x = u * eE;
  #pragma unroll
  for (int s = 32; s > 0; s >>= 1) x += __shfl_xor(x, s, 64);
  if (lane == 0) out[b] = num - (__logf(x) + ls);
}

extern "C" void kernel_launch(void* const* d_in, const int* in_sizes, int n_in,
                              void* d_out, int out_size, void* d_ws, size_t ws_size,
                              hipStream_t stream) {
  const float* H      = (const float*)d_in[0];
  const float* W      = (const float*)d_in[1];
  const float* bias   = (const float*)d_in[2];
  const float* startT = (const float*)d_in[3];
  const float* endT   = (const float*)d_in[4];
  const float* trans  = (const float*)d_in[5];
  const int*   y      = (const int*)d_in[6];
  const int*   y_len  = (const int*)d_in[8];
  float* out = (float*)d_out;

  crf_fused_kernel<<<dim3(256), dim3(512), 0, stream>>>(
      H, W, bias, startT, endT, trans, y, y_len, out);
}

// Round 6
// 46.307 us; speedup vs baseline: 1.7431x; 1.2037x over previous
//
#include <hip/hip_runtime.h>

typedef __attribute__((ext_vector_type(8))) short short8;
typedef __attribute__((ext_vector_type(4))) float f32x4;
typedef __fp16 h2_t __attribute__((ext_vector_type(2)));

__device__ __forceinline__ unsigned pk_rtz(float a, float b) {
  h2_t h = __builtin_amdgcn_cvt_pkrtz(a, b);
  return __builtin_bit_cast(unsigned, h);
}
__device__ __forceinline__ unsigned pk_rne(float a, float b) {
  unsigned short ha = __builtin_bit_cast(unsigned short, (_Float16)a);
  unsigned short hb = __builtin_bit_cast(unsigned short, (_Float16)b);
  return (unsigned)ha | ((unsigned)hb << 16);
}
__device__ __forceinline__ unsigned short f2bf(float x) {
  unsigned int u = __float_as_uint(x);
  u += 0x7FFFu + ((u >> 16) & 1u);
  return (unsigned short)(u >> 16);
}
__device__ __forceinline__ unsigned scale_bf_pair(unsigned w, float s) {
  float f0 = __uint_as_float(w << 16) * s;
  float f1 = __uint_as_float(w & 0xFFFF0000u) * s;
  unsigned r;
  asm("v_cvt_pk_bf16_f32 %0, %1, %2" : "=v"(r) : "v"(f0), "v"(f1));
  return r;
}

__global__ __launch_bounds__(512) void crf_fused_kernel(
    const float* __restrict__ H, const float* __restrict__ W,
    const float* __restrict__ bias,
    const float* __restrict__ startT, const float* __restrict__ endT,
    const float* __restrict__ trans,
    const int* __restrict__ y, const int* __restrict__ y_len,
    float* __restrict__ out)
{
  // union region: GEMM staging f16 (aTh 16K | aTl 16K | bTh 24K = 56K) /
  //               P[128][196] f32 (100,352 B) / scan Mbuf 8 x 8KB (64K)
  __shared__ __align__(16) float smem[25088];
  __shared__ __align__(16) unsigned char EAbuf[8192];  // bf16 [64][128B]
  __shared__ __align__(16) float sc[128][68];          // padded stride
  __shared__ float scm[128];
  __shared__ float emy[128];
  __shared__ __align__(16) float ubuf[64];
  unsigned char* aTh = (unsigned char*)smem;
  unsigned char* aTl = aTh + 16384;
  unsigned char* bTh = aTh + 32768;
  float* P = smem;                        // [128][196]
  unsigned char* Mbase = (unsigned char*)smem;  // scan phase, 64 KB

  const int b    = blockIdx.x;
  const int tid  = threadIdx.x;
  const int lane = tid & 63;
  const int wid  = tid >> 6;
  const int wm   = wid >> 2;
  const int wn   = wid & 3;

  f32x4 acc[4][3] = {};
  const float* Hb = H + (size_t)b * (128 * 512);
  const int len = y_len[b];
  const int* yb = y + b * 128;

  // ---- issue first GEMM tile loads ----
  float4 areg[4], breg[6];
  int aRow[4], aK4[4], bN[6], bK4[6];
  #pragma unroll
  for (int it = 0; it < 4; ++it) { int i = it * 512 + tid; aRow[it] = i >> 4; aK4[it] = i & 15; }
  #pragma unroll
  for (int it = 0; it < 6; ++it) { int i = it * 512 + tid; bN[it] = i >> 4; bK4[it] = i & 15; }
  #pragma unroll
  for (int it = 0; it < 4; ++it)
    areg[it] = ((const float4*)(Hb + aRow[it] * 512))[aK4[it]];
  #pragma unroll
  for (int it = 0; it < 6; ++it)
    breg[it] = ((const float4*)(W + (bN[it] & 63) * 1536 + (bN[it] >> 6) * 512))[bK4[it]];

  // ---- EA build (coalesced trans reads, transposed swizzled scatter) ----
  // EA[r][k] = bf16(exp(trans[k][r] - 1))
  #pragma unroll
  for (int it = 0; it < 2; ++it) {
    int idx = it * 512 + tid;
    int c = idx >> 4, c4 = idx & 15;   // trans row c, float4 col c4
    float4 v = ((const float4*)trans)[idx];
    #pragma unroll
    for (int e = 0; e < 4; ++e) {
      int cp = c4 * 4 + e;             // EA row
      float val = __expf(((const float*)&v)[e] - 1.0f);
      *(unsigned short*)(EAbuf + cp * 128 + ((2 * c) ^ ((cp & 7) << 4))) = f2bf(val);
    }
  }

  // ================= GEMM: f16, A hi/lo split (2 MFMAs) =================
  for (int kk = 0; kk < 512; kk += 64) {
    if (kk) __syncthreads();
    #pragma unroll
    for (int it = 0; it < 4; ++it) {
      float4 v = areg[it];
      h2_t h01 = __builtin_amdgcn_cvt_pkrtz(v.x, v.y);
      h2_t h23 = __builtin_amdgcn_cvt_pkrtz(v.z, v.w);
      float r0 = v.x - (float)h01[0];
      float r1 = v.y - (float)h01[1];
      float r2 = v.z - (float)h23[0];
      float r3 = v.w - (float)h23[1];
      uint2 hi; hi.x = __builtin_bit_cast(unsigned, h01); hi.y = __builtin_bit_cast(unsigned, h23);
      uint2 lo; lo.x = pk_rtz(r0, r1); lo.y = pk_rtz(r2, r3);
      int off = aRow[it] * 128 + ((aK4[it] * 8) ^ ((aRow[it] & 7) << 4));
      *(uint2*)(aTh + off) = hi; *(uint2*)(aTl + off) = lo;
    }
    #pragma unroll
    for (int it = 0; it < 6; ++it) {
      float4 v = breg[it];
      uint2 bh; bh.x = pk_rne(v.x, v.y); bh.y = pk_rne(v.z, v.w);
      int off = bN[it] * 128 + ((bK4[it] * 8) ^ ((bN[it] & 7) << 4));
      *(uint2*)(bTh + off) = bh;
    }
    __syncthreads();
    if (kk < 448) {
      #pragma unroll
      for (int it = 0; it < 4; ++it)
        areg[it] = ((const float4*)(Hb + aRow[it] * 512 + kk + 64))[aK4[it]];
      #pragma unroll
      for (int it = 0; it < 6; ++it)
        breg[it] = ((const float4*)(W + (bN[it] & 63) * 1536 + (bN[it] >> 6) * 512 + kk + 64))[bK4[it]];
    }
    #pragma unroll
    for (int ks = 0; ks < 2; ++ks) {
      const int kbyte = ks * 64 + ((lane >> 4) << 4);
      short8 ah[4], al[4], bh[3];
      #pragma unroll
      for (int m = 0; m < 4; ++m) {
        int row = wm * 64 + m * 16 + (lane & 15);
        int off = row * 128 + (kbyte ^ ((row & 7) << 4));
        ah[m] = *(const short8*)(aTh + off);
        al[m] = *(const short8*)(aTl + off);
      }
      #pragma unroll
      for (int n = 0; n < 3; ++n) {
        int col = wn * 48 + n * 16 + (lane & 15);
        int off = col * 128 + (kbyte ^ ((col & 7) << 4));
        bh[n] = *(const short8*)(bTh + off);
      }
      #pragma unroll
      for (int m = 0; m < 4; ++m)
        #pragma unroll
        for (int n = 0; n < 3; ++n) {
          asm("v_mfma_f32_16x16x32_f16 %0, %1, %2, %0"
              : "+v"(acc[m][n]) : "v"(ah[m]), "v"(bh[n]));
          asm("v_mfma_f32_16x16x32_f16 %0, %1, %2, %0"
              : "+v"(acc[m][n]) : "v"(al[m]), "v"(bh[n]));
        }
    }
  }
  __syncthreads();

  // acc -> P. C/D layout: col = lane&15, row = 4*(lane>>4)+j
  #pragma unroll
  for (int m = 0; m < 4; ++m)
    #pragma unroll
    for (int n = 0; n < 3; ++n) {
      int row0 = wm * 64 + m * 16 + ((lane >> 4) << 2);
      int col  = wn * 48 + n * 16 + (lane & 15);
      #pragma unroll
      for (int j = 0; j < 4; ++j)
        P[(row0 + j) * 196 + col] = acc[m][n][j];
    }
  __syncthreads();

  // epilogue: P -> sc (raw scores), fused row-max -> scm, emission-select -> emy
  #pragma unroll
  for (int it = 0; it < 4; ++it) {
    int i4 = it * 512 + tid;
    int t = i4 >> 4, c4 = i4 & 15;
    float4 s = *(const float4*)(P + t * 196 + 64 + c4 * 4);
    float4 bb = ((const float4*)bias)[c4];
    s.x += bb.x; s.y += bb.y; s.z += bb.z; s.w += bb.w;
    if (t > 0) {
      float4 g = *(const float4*)(P + (t - 1) * 196 + c4 * 4);
      s.x += g.x; s.y += g.y; s.z += g.z; s.w += g.w;
    }
    if (t < 127) {
      float4 g = *(const float4*)(P + (t + 1) * 196 + 128 + c4 * 4);
      s.x += g.x; s.y += g.y; s.z += g.z; s.w += g.w;
    }
    *(float4*)(&sc[t][c4 * 4]) = s;
    float m4 = fmaxf(fmaxf(s.x, s.y), fmaxf(s.z, s.w));
    #pragma unroll
    for (int o = 1; o < 16; o <<= 1) m4 = fmaxf(m4, __shfl_xor(m4, o, 64));
    if ((lane & 15) == 0) scm[t] = m4;
    int yt = yb[t];
    if ((yt >> 2) == c4) {
      int r = yt & 3;
      emy[t] = (r == 0) ? s.x : (r == 1) ? s.y : (r == 2) ? s.z : s.w;
    }
  }
  __syncthreads();

  // ---- transform sc -> exp(sc - m_t) (all waves); numerator (wave 0) ----
  {
    int row = tid >> 2, c0 = (tid & 3) << 4;
    float mt = scm[row];
    float4* p4 = (float4*)&sc[row][c0];
    #pragma unroll
    for (int j = 0; j < 4; ++j) {
      float4 x = p4[j];
      x.x = __expf(x.x - mt); x.y = __expf(x.y - mt);
      x.z = __expf(x.z - mt); x.w = __expf(x.w - mt);
      p4[j] = x;
    }
  }
  float num = 0.f;
  if (wid == 0) {
    float p = 0.f;
    #pragma unroll
    for (int rep = 0; rep < 2; ++rep) {
      int t = lane + rep * 64;
      if (t < 127) {
        int yt = yb[t], yt1 = yb[t + 1];
        if (t < len)     p += emy[t];
        if (t + 1 < len) p += trans[yt * 64 + yt1];
      }
    }
    #pragma unroll
    for (int s = 32; s > 0; s >>= 1) p += __shfl_xor(p, s, 64);
    num = p + startT[yb[0]] + endT[yb[len - 1]];
    if (len == 128) num += emy[127];
  }
  __syncthreads();

  // ---- chunk phase: wave w builds B_w = prod A_t, t in [t0, t1] ----
  {
    unsigned char* Mb = Mbase + wid * 8192;
    int t0 = (wid == 0) ? 1 : 16 * wid;
    int t1 = 16 * wid + 15; if (t1 > len - 1) t1 = len - 1;
    if (t0 <= t1) {
      // init M = A_{t0}: M[r][2c] = EA[r][c] * s_{t0}[r], r = lane
      const int sw = (lane & 7) << 4;
      float s0 = sc[t0][lane];
      #pragma unroll
      for (int j = 0; j < 8; ++j) {
        uint4 w = *(const uint4*)(EAbuf + lane * 128 + ((j * 16) ^ sw));
        uint4 o;
        o.x = scale_bf_pair(w.x, s0); o.y = scale_bf_pair(w.y, s0);
        o.z = scale_bf_pair(w.z, s0); o.w = scale_bf_pair(w.w, s0);
        *(uint4*)(Mb + lane * 128 + ((j * 16) ^ sw)) = o;
      }
      short8 ea[4][2];
      #pragma unroll
      for (int rt = 0; rt < 4; ++rt)
        #pragma unroll
        for (int kh = 0; kh < 2; ++kh) {
          int row = rt * 16 + (lane & 15);
          int kb = kh * 64 + ((lane >> 4) << 4);
          ea[rt][kh] = *(const short8*)(EAbuf + row * 128 + (kb ^ ((row & 7) << 4)));
        }
      f32x4 z4 = {0.f, 0.f, 0.f, 0.f};
      for (int t = t0 + 1; t <= t1; ++t) {
        short8 mf[4][2];
        #pragma unroll
        for (int ct = 0; ct < 4; ++ct)
          #pragma unroll
          for (int kh = 0; kh < 2; ++kh) {
            int row = ct * 16 + (lane & 15);
            int kb = kh * 64 + ((lane >> 4) << 4);
            mf[ct][kh] = *(const short8*)(Mb + row * 128 + (kb ^ ((row & 7) << 4)));
          }
        f32x4 sv[4];
        #pragma unroll
        for (int rt = 0; rt < 4; ++rt)
          sv[rt] = *(const f32x4*)(&sc[t][rt * 16 + ((lane >> 4) << 2)]);
        f32x4 c[4][4];
        #pragma unroll
        for (int rt = 0; rt < 4; ++rt)
          #pragma unroll
          for (int ct = 0; ct < 4; ++ct) {
            asm("v_mfma_f32_16x16x32_bf16 %0, %1, %2, %3"
                : "=&v"(c[rt][ct]) : "v"(ea[rt][0]), "v"(mf[ct][0]), "v"(z4));
            asm("v_mfma_f32_16x16x32_bf16 %0, %1, %2, %0"
                : "+v"(c[rt][ct]) : "v"(ea[rt][1]), "v"(mf[ct][1]));
          }
        #pragma unroll
        for (int rt = 0; rt < 4; ++rt)
          #pragma unroll
          for (int ct = 0; ct < 4; ++ct) {
            f32x4 cc = c[rt][ct] * sv[rt];
            unsigned p0, p1;
            asm("v_cvt_pk_bf16_f32 %0, %1, %2" : "=v"(p0) : "v"(cc[0]), "v"(cc[1]));
            asm("v_cvt_pk_bf16_f32 %0, %1, %2" : "=v"(p1) : "v"(cc[2]), "v"(cc[3]));
            uint2 w2; w2.x = p0; w2.y = p1;
            int row = ct * 16 + (lane & 15);
            int byt = 2 * (rt * 16 + ((lane >> 4) << 2));
            *(uint2*)(Mb + row * 128 + (byt ^ ((row & 7) << 4))) = w2;
          }
      }
    }
  }
  __syncthreads();
  if (wid != 0) return;

  // ---- wave 0: combine u^T B_0 ... B_7, then logZ ----
  float eE = __expf(endT[lane]);
  float ls;
  {
    int t1 = 1 + lane, t2 = 65 + lane;
    float a = (t1 <= len - 1) ? (scm[t1] + 1.0f) : 0.f;
    if (t2 <= len - 1) a += scm[t2] + 1.0f;
    #pragma unroll
    for (int s = 32; s > 0; s >>= 1) a += __shfl_xor(a, s, 64);
    ls = a + scm[0];
  }
  float u = __expf(startT[lane]) * sc[0][lane];

  for (int k = 0; k < 8; ++k) {
    if (16 * k >= len) break;
    int lo = (k == 0) ? 1 : 16 * k;
    int hi = 16 * k + 15; if (hi > len - 1) hi = len - 1;
    if (lo > hi) continue;
    float r = u;
    #pragma unroll
    for (int s = 32; s > 0; s >>= 1) r = fmaxf(r, __shfl_xor(r, s, 64));
    unsigned br = __float_as_uint(r) & 0x7F800000u;
    u *= __uint_as_float(0x7F000000u - br);
    ls += (float)((int)(br >> 23) - 127) * 0.69314718055994531f;
    const unsigned char* Mb = Mbase + k * 8192;
    ubuf[lane] = u;
    float v = 0.f;
    #pragma unroll 4
    for (int c = 0; c < 64; c += 4) {
      float4 uu = *(const float4*)&ubuf[c];
      float m0 = __uint_as_float(((unsigned)*(const unsigned short*)(Mb + (c + 0) * 128 + ((2 * lane) ^ (((c + 0) & 7) << 4)))) << 16);
      float m1 = __uint_as_float(((unsigned)*(const unsigned short*)(Mb + (c + 1) * 128 + ((2 * lane) ^ (((c + 1) & 7) << 4)))) << 16);
      float m2 = __uint_as_float(((unsigned)*(const unsigned short*)(Mb + (c + 2) * 128 + ((2 * lane) ^ (((c + 2) & 7) << 4)))) << 16);
      float m3 = __uint_as_float(((unsigned)*(const unsigned short*)(Mb + (c + 3) * 128 + ((2 * lane) ^ (((c + 3) & 7) << 4)))) << 16);
      v = fmaf(uu.x, m0, v);
      v = fmaf(uu.y, m1, v);
      v = fmaf(uu.z, m2, v);
      v = fmaf(uu.w, m3, v);
    }
    u = v;
  }

  float x = u * eE;
  #pragma unroll
  for (int s = 32; s > 0; s >>= 1) x += __shfl_xor(x, s, 64);
  if (lane == 0) out[b] = num - (__logf(x) + ls);
}

extern "C" void kernel_launch(void* const* d_in, const int* in_sizes, int n_in,
                              void* d_out, int out_size, void* d_ws, size_t ws_size,
                              hipStream_t stream) {
  const float* H      = (const float*)d_in[0];
  const float* W      = (const float*)d_in[1];
  const float* bias   = (const float*)d_in[2];
  const float* startT = (const float*)d_in[3];
  const float* endT   = (const float*)d_in[4];
  const float* trans  = (const float*)d_in[5];
  const int*   y      = (const int*)d_in[6];
  const int*   y_len  = (const int*)d_in[8];
  float* out = (float*)d_out;

  crf_fused_kernel<<<dim3(256), dim3(512), 0, stream>>>(
      H, W, bias, startT, endT, trans, y, y_len, out);
}